// Round 5
// baseline (263.321 us; speedup 1.0000x reference)
//
#include <hip/hip_runtime.h>

// Problem constants (reference: B=256, L=512, N=4)
constexpr int B = 256;
constexpr int NCHUNK = 16;            // j's per block
constexpr int NSLOT  = 255 * 16;      // 4080 slab slots (one per block)

#define MARGIN 1e-3f
#define LOG2E  1.4426950408889634f
#define LN2    0.6931471805599453

// ---- workspace layout (bytes); all locations read are written every call ----
constexpr size_t OFF_SLAB = 0;        // float slab[4080][4]   (65280 B)
constexpr size_t OFF_CNT  = 65536;    // float cntp[8][4]      (128 B)
constexpr size_t OFF_PSC  = 69632;    // float psc[256*512*4]  (2 MB) preds*log2e
constexpr size_t OFF_PK   = 2166784;  // uchar pk[256][256]    (64 KB) packed masks

// ---------------------------------------------------------------------------
// Prep: b<512  : psc = preds * log2e (float4 streaming)
//       b<768  : pack masks -> 1 byte per (row, lane): bits = dl*4+n, l=2t+dl
//       b<776  : cntp[p][n] = exact masked-pair count partials via column
//                popcounts: mask_sum[n] = sum_l C(colcount(l,n), 2)
// ---------------------------------------------------------------------------
__global__ __launch_bounds__(256) void prep_kernel(
    const float* __restrict__ preds,
    const int*   __restrict__ masks,
    float*        __restrict__ psc,
    unsigned char* __restrict__ pk,
    float*        __restrict__ cntp)
{
    const int b = blockIdx.x;
    const int t = threadIdx.x;
    __shared__ float sredc[256];

    if (b < 512) {
        const int idx = b * 256 + t;                  // float4 index
        float4 v = ((const float4*)preds)[idx];
        v.x *= LOG2E; v.y *= LOG2E; v.z *= LOG2E; v.w *= LOG2E;
        ((float4*)psc)[idx] = v;
    } else if (b < 768) {
        const int r = b - 512;                        // mask row
        const int4 m0 = ((const int4*)masks)[r * 512 + 2 * t];      // l = 2t
        const int4 m1 = ((const int4*)masks)[r * 512 + 2 * t + 1];  // l = 2t+1
        const unsigned byte =
            (unsigned)m0.x | ((unsigned)m0.y << 1) | ((unsigned)m0.z << 2) |
            ((unsigned)m0.w << 3) | ((unsigned)m1.x << 4) | ((unsigned)m1.y << 5) |
            ((unsigned)m1.z << 6) | ((unsigned)m1.w << 7);
        pk[r * 256 + t] = (unsigned char)byte;
    } else {
        const int p   = b - 768;                      // 0..7
        const int col = p * 256 + t;                  // (l, n) column
        int c = 0;
        #pragma unroll 8
        for (int r = 0; r < 256; ++r) c += masks[r * 2048 + col];
        sredc[t] = (float)((c * (c - 1)) / 2);        // C(c,2) exact in f32
        __syncthreads();
        if (t < 4) {                                  // n = col & 3 = t
            float s = 0.f;
            for (int q = t; q < 256; q += 4) s += sredc[q];
            cntp[p * 4 + t] = s;                      // non-atomic, fixed slot
        }
    }
}

// ---------------------------------------------------------------------------
// Main: block = (chunk, i). Fixed row i in registers; 16 j's streamed
// branchlessly (j clamped to 255, invalid j zero-masked via scalar select).
// Loss in base-2 units: bce/ln2 = log2(1 + 2^u) - tg*u,  u = (pi-pj)*log2e.
// Per-block partial written to a private slab slot (no atomics).
// ---------------------------------------------------------------------------
__global__ __launch_bounds__(256, 8) void pair_bce_kernel(
    const float* __restrict__ targets,
    const float* __restrict__ psc,          // scaled preds
    const unsigned char* __restrict__ pk,   // packed masks
    float* __restrict__ slab)               // [4080][4]
{
    const int i     = blockIdx.y;           // 0..254
    const int chunk = blockIdx.x;           // 0..15
    const int t     = threadIdx.x;
    const int slot  = (i * NCHUNK + chunk) * 4;
    const int j0    = i + 1 + chunk * NCHUNK;

    if (j0 >= B) {                          // no valid pairs: zero our slot
        if (t < 4) slab[slot + t] = 0.f;
        return;
    }

    const float4* psc4 = (const float4*)psc;
    const float4* tgt4 = (const float4*)targets;

    // i-row in registers: lane t owns l = 2t, 2t+1
    const float4  pi0 = psc4[i * 512 + 2 * t];
    const float4  pi1 = psc4[i * 512 + 2 * t + 1];
    const float4  ti0 = tgt4[i * 512 + 2 * t];
    const float4  ti1 = tgt4[i * 512 + 2 * t + 1];
    const unsigned mi = pk[i * 256 + t];

    float loss[4] = {0.f, 0.f, 0.f, 0.f};

#define ELEM(nn, bit, PI, PJ, TI, TJ)                                          \
    {                                                                          \
        const float u  = (PI) - (PJ);                                          \
        const float sp = __builtin_log2f(1.0f + __builtin_exp2f(u));           \
        const float td = (TI) - (TJ);                                          \
        const float ut = (td > MARGIN) ? u : 0.0f;                             \
        const float r  = sp - ut;                                              \
        loss[nn] += (float)((mp >> (bit)) & 1u) * r;                           \
    }

    #pragma unroll
    for (int c = 0; c < NCHUNK; ++c) {
        const int j  = j0 + c;                        // block-uniform
        const int jc = (j < B) ? j : (B - 1);         // clamp (loads stay legal)
        const float4  pj0 = psc4[jc * 512 + 2 * t];
        const float4  pj1 = psc4[jc * 512 + 2 * t + 1];
        const float4  tj0 = tgt4[jc * 512 + 2 * t];
        const float4  tj1 = tgt4[jc * 512 + 2 * t + 1];
        const unsigned mj = pk[jc * 256 + t];
        const unsigned mp = mi & mj & ((j < B) ? 0xFFu : 0u);

        ELEM(0, 0, pi0.x, pj0.x, ti0.x, tj0.x);
        ELEM(1, 1, pi0.y, pj0.y, ti0.y, tj0.y);
        ELEM(2, 2, pi0.z, pj0.z, ti0.z, tj0.z);
        ELEM(3, 3, pi0.w, pj0.w, ti0.w, tj0.w);
        ELEM(0, 4, pi1.x, pj1.x, ti1.x, tj1.x);
        ELEM(1, 5, pi1.y, pj1.y, ti1.y, tj1.y);
        ELEM(2, 6, pi1.z, pj1.z, ti1.z, tj1.z);
        ELEM(3, 7, pi1.w, pj1.w, ti1.w, tj1.w);
    }
#undef ELEM

    // ---- block reduction: wave shuffle (64 lanes) -> LDS across 4 waves ----
    #pragma unroll
    for (int kk = 0; kk < 4; kk++) {
        #pragma unroll
        for (int off = 32; off > 0; off >>= 1)
            loss[kk] += __shfl_down(loss[kk], off, 64);
    }

    __shared__ float sred[4][4];
    if ((t & 63) == 0) {
        #pragma unroll
        for (int kk = 0; kk < 4; kk++) sred[t >> 6][kk] = loss[kk];
    }
    __syncthreads();

    if (t < 4)
        slab[slot + t] = sred[0][t] + sred[1][t] + sred[2][t] + sred[3][t];
}

// ---------------------------------------------------------------------------
// Finalize: total = (1/4) * sum_n where(cnt>0, ln2 * loss2_n / (cnt_n+EPS), 0)
// ---------------------------------------------------------------------------
__global__ __launch_bounds__(256) void finalize_kernel(
    const float* __restrict__ slab,
    const float* __restrict__ cntp,
    float* __restrict__ out)
{
    const int t = threadIdx.x;
    const int n = t & 3, g = t >> 2;          // 64 groups x 4 features
    double s = 0.0;
    for (int q = g; q < NSLOT; q += 64) s += (double)slab[q * 4 + n];

    __shared__ double sd[260];
    sd[t] = s;
    __syncthreads();

    if (t < 4) {
        double ls = 0.0;
        for (int g2 = 0; g2 < 64; ++g2) ls += sd[g2 * 4 + t];
        double cs = 0.0;
        for (int p = 0; p < 8; ++p) cs += (double)cntp[p * 4 + t];
        sd[256 + t] = (cs > 0.0) ? (LN2 * ls / (cs + 1e-8)) : 0.0;
    }
    __syncthreads();

    if (t == 0)
        out[0] = (float)((sd[256] + sd[257] + sd[258] + sd[259]) * 0.25);
}

extern "C" void kernel_launch(void* const* d_in, const int* in_sizes, int n_in,
                              void* d_out, int out_size, void* d_ws, size_t ws_size,
                              hipStream_t stream)
{
    const float* preds   = (const float*)d_in[0];
    const float* targets = (const float*)d_in[1];
    const int*   masks   = (const int*)d_in[2];   // jnp.bool_ arrives as int32
    float* out = (float*)d_out;

    char* ws = (char*)d_ws;
    float*         slab = (float*)(ws + OFF_SLAB);
    float*         cntp = (float*)(ws + OFF_CNT);
    float*         psc  = (float*)(ws + OFF_PSC);
    unsigned char* pk   = (unsigned char*)(ws + OFF_PK);

    prep_kernel<<<776, 256, 0, stream>>>(preds, masks, psc, pk, cntp);
    pair_bce_kernel<<<dim3(NCHUNK, B - 1), 256, 0, stream>>>(targets, psc, pk, slab);
    finalize_kernel<<<1, 256, 0, stream>>>(slab, cntp, out);
}

// Round 6
// 113.095 us; speedup vs baseline: 2.3283x; 2.3283x over previous
//
#include <hip/hip_runtime.h>

// Problem constants (reference: B=256, L=512, N=4)
constexpr int B = 256;
constexpr int NCHUNK = 16;            // j's per block
constexpr int NSLOT  = 255 * 16;      // 4080 slab slots (one per block)

#define MARGIN 1e-3f
#define LOG2E  1.4426950408889634f
#define LN2    0.6931471805599453

// ---- workspace layout (bytes); all locations read are written every call ----
constexpr size_t OFF_SLAB = 0;        // float slab[4080][4]   (65280 B)
constexpr size_t OFF_CNT  = 65536;    // float cntp[8][4]      (128 B)
constexpr size_t OFF_PSC  = 69632;    // float psc[256*512*4]  (2 MB) preds*log2e
constexpr size_t OFF_PK   = 2166784;  // uchar pk[256][256]    (64 KB) packed masks

// ---------------------------------------------------------------------------
// Prep: b<512  : psc = preds * log2e (float4 streaming)
//       b<768  : pack masks -> 1 byte per (row, lane): bits 0..3 = l=t (n=0..3),
//                bits 4..7 = l=t+256 (n=0..3)
//       b<776  : cntp[p][n] = exact masked-pair count partials via column
//                popcounts: mask_sum[n] = sum_l C(colcount(l,n), 2)
// ---------------------------------------------------------------------------
__global__ __launch_bounds__(256) void prep_kernel(
    const float* __restrict__ preds,
    const int*   __restrict__ masks,
    float*        __restrict__ psc,
    unsigned char* __restrict__ pk,
    float*        __restrict__ cntp)
{
    const int b = blockIdx.x;
    const int t = threadIdx.x;
    __shared__ float sredc[256];

    if (b < 512) {
        const int idx = b * 256 + t;                  // float4 index
        float4 v = ((const float4*)preds)[idx];
        v.x *= LOG2E; v.y *= LOG2E; v.z *= LOG2E; v.w *= LOG2E;
        ((float4*)psc)[idx] = v;
    } else if (b < 768) {
        const int r = b - 512;                        // mask row
        const int4 m0 = ((const int4*)masks)[r * 512 + t];        // l = t
        const int4 m1 = ((const int4*)masks)[r * 512 + t + 256];  // l = t+256
        const unsigned byte =
            (unsigned)m0.x | ((unsigned)m0.y << 1) | ((unsigned)m0.z << 2) |
            ((unsigned)m0.w << 3) | ((unsigned)m1.x << 4) | ((unsigned)m1.y << 5) |
            ((unsigned)m1.z << 6) | ((unsigned)m1.w << 7);
        pk[r * 256 + t] = (unsigned char)byte;
    } else {
        const int p   = b - 768;                      // 0..7
        const int col = p * 256 + t;                  // (l, n) column
        int c = 0;
        #pragma unroll 8
        for (int r = 0; r < 256; ++r) c += masks[r * 2048 + col];
        sredc[t] = (float)((c * (c - 1)) / 2);        // C(c,2) exact in f32
        __syncthreads();
        if (t < 4) {                                  // n = col & 3 = t
            float s = 0.f;
            for (int q = t; q < 256; q += 4) s += sredc[q];
            cntp[p * 4 + t] = s;                      // non-atomic, fixed slot
        }
    }
}

// ---------------------------------------------------------------------------
// Main: block = (chunk, i). Fixed row i in registers; 16 j's streamed
// branchlessly (j clamped to 255, invalid j zero-masked via scalar select).
// Loss in base-2 units: bce/ln2 = log2(1 + 2^u) - tg*u,  u = (pi-pj)*log2e.
// Per-block partial written to a private slab slot (no atomics).
// __launch_bounds__(256,4): VGPR cap 128 — roomy, no scratch spill (round-5
// lesson: min-waves=8 capped VGPR at 32 and spilled 380 MB to scratch).
// ---------------------------------------------------------------------------
__global__ __launch_bounds__(256, 4) void pair_bce_kernel(
    const float* __restrict__ targets,
    const float* __restrict__ psc,          // scaled preds
    const unsigned char* __restrict__ pk,   // packed masks
    float* __restrict__ slab)               // [4080][4]
{
    const int i     = blockIdx.y;           // 0..254
    const int chunk = blockIdx.x;           // 0..15
    const int t     = threadIdx.x;
    const int slot  = (i * NCHUNK + chunk) * 4;
    const int j0    = i + 1 + chunk * NCHUNK;

    if (j0 >= B) {                          // no valid pairs: zero our slot
        if (t < 4) slab[slot + t] = 0.f;
        return;
    }

    const float4* psc4 = (const float4*)psc;
    const float4* tgt4 = (const float4*)targets;

    // i-row in registers: lane t owns l = t and l = t+256 (coalesced 16B)
    const float4  pi0 = psc4[i * 512 + t];
    const float4  pi1 = psc4[i * 512 + t + 256];
    const float4  ti0 = tgt4[i * 512 + t];
    const float4  ti1 = tgt4[i * 512 + t + 256];
    const unsigned mi = pk[i * 256 + t];

    float loss[4] = {0.f, 0.f, 0.f, 0.f};

#define ELEM(nn, bit, PI, PJ, TI, TJ)                                          \
    {                                                                          \
        const float u  = (PI) - (PJ);                                          \
        const float sp = __builtin_log2f(1.0f + __builtin_exp2f(u));           \
        const float td = (TI) - (TJ);                                          \
        const float ut = (td > MARGIN) ? u : 0.0f;                             \
        const float r  = sp - ut;                                              \
        loss[nn] += (float)((mp >> (bit)) & 1u) * r;                           \
    }

    #pragma unroll 4
    for (int c = 0; c < NCHUNK; ++c) {
        const int j  = j0 + c;                        // block-uniform
        const int jc = (j < B) ? j : (B - 1);         // clamp (loads stay legal)
        const float4  pj0 = psc4[jc * 512 + t];
        const float4  pj1 = psc4[jc * 512 + t + 256];
        const float4  tj0 = tgt4[jc * 512 + t];
        const float4  tj1 = tgt4[jc * 512 + t + 256];
        const unsigned mj = pk[jc * 256 + t];
        const unsigned mp = mi & mj & ((j < B) ? 0xFFu : 0u);

        ELEM(0, 0, pi0.x, pj0.x, ti0.x, tj0.x);
        ELEM(1, 1, pi0.y, pj0.y, ti0.y, tj0.y);
        ELEM(2, 2, pi0.z, pj0.z, ti0.z, tj0.z);
        ELEM(3, 3, pi0.w, pj0.w, ti0.w, tj0.w);
        ELEM(0, 4, pi1.x, pj1.x, ti1.x, tj1.x);
        ELEM(1, 5, pi1.y, pj1.y, ti1.y, tj1.y);
        ELEM(2, 6, pi1.z, pj1.z, ti1.z, tj1.z);
        ELEM(3, 7, pi1.w, pj1.w, ti1.w, tj1.w);
    }
#undef ELEM

    // ---- block reduction: wave shuffle (64 lanes) -> LDS across 4 waves ----
    #pragma unroll
    for (int kk = 0; kk < 4; kk++) {
        #pragma unroll
        for (int off = 32; off > 0; off >>= 1)
            loss[kk] += __shfl_down(loss[kk], off, 64);
    }

    __shared__ float sred[4][4];
    if ((t & 63) == 0) {
        #pragma unroll
        for (int kk = 0; kk < 4; kk++) sred[t >> 6][kk] = loss[kk];
    }
    __syncthreads();

    if (t < 4)
        slab[slot + t] = sred[0][t] + sred[1][t] + sred[2][t] + sred[3][t];
}

// ---------------------------------------------------------------------------
// Finalize: total = (1/4) * sum_n where(cnt>0, ln2 * loss2_n / (cnt_n+EPS), 0)
// ---------------------------------------------------------------------------
__global__ __launch_bounds__(256) void finalize_kernel(
    const float* __restrict__ slab,
    const float* __restrict__ cntp,
    float* __restrict__ out)
{
    const int t = threadIdx.x;
    const int n = t & 3, g = t >> 2;          // 64 groups x 4 features
    double s = 0.0;
    for (int q = g; q < NSLOT; q += 64) s += (double)slab[q * 4 + n];

    __shared__ double sd[260];
    sd[t] = s;
    __syncthreads();

    if (t < 4) {
        double ls = 0.0;
        for (int g2 = 0; g2 < 64; ++g2) ls += sd[g2 * 4 + t];
        double cs = 0.0;
        for (int p = 0; p < 8; ++p) cs += (double)cntp[p * 4 + t];
        sd[256 + t] = (cs > 0.0) ? (LN2 * ls / (cs + 1e-8)) : 0.0;
    }
    __syncthreads();

    if (t == 0)
        out[0] = (float)((sd[256] + sd[257] + sd[258] + sd[259]) * 0.25);
}

extern "C" void kernel_launch(void* const* d_in, const int* in_sizes, int n_in,
                              void* d_out, int out_size, void* d_ws, size_t ws_size,
                              hipStream_t stream)
{
    const float* preds   = (const float*)d_in[0];
    const float* targets = (const float*)d_in[1];
    const int*   masks   = (const int*)d_in[2];   // jnp.bool_ arrives as int32
    float* out = (float*)d_out;

    char* ws = (char*)d_ws;
    float*         slab = (float*)(ws + OFF_SLAB);
    float*         cntp = (float*)(ws + OFF_CNT);
    float*         psc  = (float*)(ws + OFF_PSC);
    unsigned char* pk   = (unsigned char*)(ws + OFF_PK);

    prep_kernel<<<776, 256, 0, stream>>>(preds, masks, psc, pk, cntp);
    pair_bce_kernel<<<dim3(NCHUNK, B - 1), 256, 0, stream>>>(targets, psc, pk, slab);
    finalize_kernel<<<1, 256, 0, stream>>>(slab, cntp, out);
}

// Round 7
// 74.828 us; speedup vs baseline: 3.5190x; 1.5114x over previous
//
#include <hip/hip_runtime.h>

// Problem constants (reference: B=256, L=512, N=4)
constexpr int B  = 256;
constexpr int TI = 4;             // i-rows per block (in registers)
constexpr int TJ = 8;             // j's per block
constexpr int NBLK = 1056;        // sum_{g=0}^{63} ceil((255-4g)/8) -- exact

#define MARGIN 1e-3f
#define LOG2E  1.4426950408889634f
#define LN2    0.6931471805599453

// ---- workspace layout (bytes); all locations read are written every call ----
constexpr size_t OFF_SLAB = 0;        // float slab[1056][4]   (16896 B)
constexpr size_t OFF_CNT  = 65536;    // float cntp[8][4]      (128 B)
constexpr size_t OFF_PSC  = 69632;    // float psc[256*512*4]  (2 MB) preds*log2e
constexpr size_t OFF_PK   = 2166784;  // uchar pk[256][256]    (64 KB) packed masks

// ---------------------------------------------------------------------------
// Prep: b<512  : psc = preds * log2e (float4 streaming)
//       b<768  : pack masks -> 1 byte per (row, lane): bits 0..3 = l=t (n=0..3),
//                bits 4..7 = l=t+256 (n=0..3)
//       b<776  : cntp[p][n] = exact masked-pair count partials via column
//                popcounts: mask_sum[n] = sum_l C(colcount(l,n), 2)
// ---------------------------------------------------------------------------
__global__ __launch_bounds__(256) void prep_kernel(
    const float* __restrict__ preds,
    const int*   __restrict__ masks,
    float*        __restrict__ psc,
    unsigned char* __restrict__ pk,
    float*        __restrict__ cntp)
{
    const int b = blockIdx.x;
    const int t = threadIdx.x;
    __shared__ float sredc[256];

    if (b < 512) {
        const int idx = b * 256 + t;                  // float4 index
        float4 v = ((const float4*)preds)[idx];
        v.x *= LOG2E; v.y *= LOG2E; v.z *= LOG2E; v.w *= LOG2E;
        ((float4*)psc)[idx] = v;
    } else if (b < 768) {
        const int r = b - 512;                        // mask row
        const int4 m0 = ((const int4*)masks)[r * 512 + t];        // l = t
        const int4 m1 = ((const int4*)masks)[r * 512 + t + 256];  // l = t+256
        const unsigned byte =
            (unsigned)m0.x | ((unsigned)m0.y << 1) | ((unsigned)m0.z << 2) |
            ((unsigned)m0.w << 3) | ((unsigned)m1.x << 4) | ((unsigned)m1.y << 5) |
            ((unsigned)m1.z << 6) | ((unsigned)m1.w << 7);
        pk[r * 256 + t] = (unsigned char)byte;
    } else {
        const int p   = b - 768;                      // 0..7
        const int col = p * 256 + t;                  // (l, n) column
        int c = 0;
        #pragma unroll 8
        for (int r = 0; r < 256; ++r) c += masks[r * 2048 + col];
        sredc[t] = (float)((c * (c - 1)) / 2);        // C(c,2) exact in f32
        __syncthreads();
        if (t < 4) {                                  // n = col & 3 = t
            float s = 0.f;
            for (int q = t; q < 256; q += 4) s += sredc[q];
            cntp[p * 4 + t] = s;                      // non-atomic, fixed slot
        }
    }
}

// ---------------------------------------------------------------------------
// Main: block bid -> (g, c): i-tile = rows [4g, 4g+4) held in registers,
// j in [4g+1+8c, 4g+1+8c+8). Each j-row load is reused for 4 pairs (4x less
// load/addr overhead than 1-row blocks; ~340 VALU between dependent loads).
// Invalid pairs (i>=j or j>=256) zero-masked via scalar select.
// ELEM identity: bce/ln2 = log2(1+2^u) - tg*u = log2(1 + 2^(tg ? -u : u)).
// Exactly NBLK=1056 full-work blocks, ~1 residency round at 4 blocks/CU.
// ---------------------------------------------------------------------------
__global__ __launch_bounds__(256, 4) void pair_bce_kernel(
    const float* __restrict__ targets,
    const float* __restrict__ psc,          // scaled preds
    const unsigned char* __restrict__ pk,   // packed masks
    float* __restrict__ slab)               // [NBLK][4]
{
    const int bid = blockIdx.x;
    const int t   = threadIdx.x;

    // unrank bid -> (g, c);  cg = ceil((255-4g)/8) = (262-4g)>>3
    int g = 0, s = 0;
    for (;;) {
        const int cg = (262 - 4 * g) >> 3;
        if (s + cg > bid) break;
        s += cg; ++g;
    }
    const int c     = bid - s;
    const int i0    = 4 * g;
    const int jbase = i0 + 1 + 8 * c;

    const float4* psc4 = (const float4*)psc;
    const float4* tgt4 = (const float4*)targets;

    // i-tile in registers: lane t owns l = t and l = t+256 (coalesced 16B)
    float4 pi0[TI], pi1[TI], ti0[TI], ti1[TI];
    unsigned mi[TI];
    #pragma unroll
    for (int r = 0; r < TI; ++r) {
        pi0[r] = psc4[(i0 + r) * 512 + t];
        pi1[r] = psc4[(i0 + r) * 512 + t + 256];
        ti0[r] = tgt4[(i0 + r) * 512 + t];
        ti1[r] = tgt4[(i0 + r) * 512 + t + 256];
        mi[r]  = pk[(i0 + r) * 256 + t];
    }

    float loss[4] = {0.f, 0.f, 0.f, 0.f};

#define ELEM(nn, bit, PIv, PJv, TIv, TJv)                                      \
    {                                                                          \
        const float u  = (PIv) - (PJv);                                        \
        const float td = (TIv) - (TJv);                                        \
        const float up = (td > MARGIN) ? -u : u;                               \
        const float sp = __builtin_log2f(1.0f + __builtin_exp2f(up));          \
        loss[nn] = __builtin_fmaf((float)((mp >> (bit)) & 1u), sp, loss[nn]);  \
    }

    #pragma unroll 2
    for (int cc = 0; cc < TJ; ++cc) {
        const int j  = jbase + cc;                    // block-uniform
        const int jc = (j < B) ? j : (B - 1);         // clamp (loads stay legal)
        const float4  pj0 = psc4[jc * 512 + t];
        const float4  pj1 = psc4[jc * 512 + t + 256];
        const float4  tj0 = tgt4[jc * 512 + t];
        const float4  tj1 = tgt4[jc * 512 + t + 256];
        const unsigned mjv = pk[jc * 256 + t];

        #pragma unroll
        for (int r = 0; r < TI; ++r) {
            const unsigned ok = (((i0 + r) < j) && (j < B)) ? 0xFFu : 0u;
            const unsigned mp = mi[r] & mjv & ok;

            ELEM(0, 0, pi0[r].x, pj0.x, ti0[r].x, tj0.x);
            ELEM(1, 1, pi0[r].y, pj0.y, ti0[r].y, tj0.y);
            ELEM(2, 2, pi0[r].z, pj0.z, ti0[r].z, tj0.z);
            ELEM(3, 3, pi0[r].w, pj0.w, ti0[r].w, tj0.w);
            ELEM(0, 4, pi1[r].x, pj1.x, ti1[r].x, tj1.x);
            ELEM(1, 5, pi1[r].y, pj1.y, ti1[r].y, tj1.y);
            ELEM(2, 6, pi1[r].z, pj1.z, ti1[r].z, tj1.z);
            ELEM(3, 7, pi1[r].w, pj1.w, ti1[r].w, tj1.w);
        }
    }
#undef ELEM

    // ---- block reduction: wave shuffle (64 lanes) -> LDS across 4 waves ----
    #pragma unroll
    for (int kk = 0; kk < 4; kk++) {
        #pragma unroll
        for (int off = 32; off > 0; off >>= 1)
            loss[kk] += __shfl_down(loss[kk], off, 64);
    }

    __shared__ float sred[4][4];
    if ((t & 63) == 0) {
        #pragma unroll
        for (int kk = 0; kk < 4; kk++) sred[t >> 6][kk] = loss[kk];
    }
    __syncthreads();

    if (t < 4)
        slab[bid * 4 + t] = sred[0][t] + sred[1][t] + sred[2][t] + sred[3][t];
}

// ---------------------------------------------------------------------------
// Finalize: total = (1/4) * sum_n where(cnt>0, ln2 * loss2_n / (cnt_n+EPS), 0)
// ---------------------------------------------------------------------------
__global__ __launch_bounds__(256) void finalize_kernel(
    const float* __restrict__ slab,
    const float* __restrict__ cntp,
    float* __restrict__ out)
{
    const int t = threadIdx.x;
    const int n = t & 3, g = t >> 2;          // 64 groups x 4 features
    double s = 0.0;
    for (int q = g; q < NBLK; q += 64) s += (double)slab[q * 4 + n];

    __shared__ double sd[260];
    sd[t] = s;
    __syncthreads();

    if (t < 4) {
        double ls = 0.0;
        for (int g2 = 0; g2 < 64; ++g2) ls += sd[g2 * 4 + t];
        double cs = 0.0;
        for (int p = 0; p < 8; ++p) cs += (double)cntp[p * 4 + t];
        sd[256 + t] = (cs > 0.0) ? (LN2 * ls / (cs + 1e-8)) : 0.0;
    }
    __syncthreads();

    if (t == 0)
        out[0] = (float)((sd[256] + sd[257] + sd[258] + sd[259]) * 0.25);
}

extern "C" void kernel_launch(void* const* d_in, const int* in_sizes, int n_in,
                              void* d_out, int out_size, void* d_ws, size_t ws_size,
                              hipStream_t stream)
{
    const float* preds   = (const float*)d_in[0];
    const float* targets = (const float*)d_in[1];
    const int*   masks   = (const int*)d_in[2];   // jnp.bool_ arrives as int32
    float* out = (float*)d_out;

    char* ws = (char*)d_ws;
    float*         slab = (float*)(ws + OFF_SLAB);
    float*         cntp = (float*)(ws + OFF_CNT);
    float*         psc  = (float*)(ws + OFF_PSC);
    unsigned char* pk   = (unsigned char*)(ws + OFF_PK);

    prep_kernel<<<776, 256, 0, stream>>>(preds, masks, psc, pk, cntp);
    pair_bce_kernel<<<NBLK, 256, 0, stream>>>(targets, psc, pk, slab);
    finalize_kernel<<<1, 256, 0, stream>>>(slab, cntp, out);
}